// Round 10
// baseline (51.228 us; speedup 1.0000x reference)
//
#include <hip/hip_runtime.h>
#include <hip/hip_bf16.h>

#define B_ROWS 4096
#define D_FEAT 512

typedef short s16x8 __attribute__((ext_vector_type(8)));
typedef float f32x4 __attribute__((ext_vector_type(4)));

#define GLOAD_LDS16(gsrc, ldst)                                                        \
    __builtin_amdgcn_global_load_lds(                                                  \
        (const __attribute__((address_space(1))) void*)(gsrc),                         \
        (__attribute__((address_space(3))) void*)(ldst), 16, 0, 0)

__device__ inline float waveReduceSum(float v) {
#pragma unroll
    for (int off = 32; off > 0; off >>= 1) v += __shfl_xor(v, off);
    return v;
}

// ---- prep: fp32->bf16 convert + sqnorm(rounded) + ws init; blocks 0..15 also do focal+KD ----
__global__ __launch_bounds__(256) void prep_kernel(const float* __restrict__ feat,
                                                   const float* __restrict__ logits,
                                                   const int* __restrict__ labels,
                                                   const float* __restrict__ soft,
                                                   short* __restrict__ featbf,
                                                   float* __restrict__ sqn,
                                                   unsigned* __restrict__ posmax,
                                                   float* __restrict__ negminf,
                                                   float* __restrict__ fpart,
                                                   float* __restrict__ kpart) {
    const int bid = blockIdx.x, tid = threadIdx.x;
    const int wave = tid >> 6, lane = tid & 63;
    const int row = bid * 4 + wave;

    const float* p = feat + (size_t)row * D_FEAT + lane * 8;
    float4 a = *(const float4*)p;
    float4 b = *(const float4*)(p + 4);
    float vals[8] = {a.x, a.y, a.z, a.w, b.x, b.y, b.z, b.w};
    short outv[8];
    float s = 0.f;
#pragma unroll
    for (int j = 0; j < 8; ++j) {
        __hip_bfloat16 h = __float2bfloat16(vals[j]);
        outv[j] = *(short*)&h;
        float xb = __bfloat162float(h);
        s = fmaf(xb, xb, s);
    }
    *(s16x8*)(featbf + (size_t)row * D_FEAT + lane * 8) = *(s16x8*)outv;
    s = waveReduceSum(s);
    if (lane == 0) sqn[row] = s;

    if (tid < 4) posmax[bid * 4 + tid] = 0u;
    else if (tid < 8) negminf[bid * 4 + tid - 4] = 1e12f;

    if (bid < 16) {
        int i = bid * 256 + tid;
        float l0 = logits[2 * i], l1 = logits[2 * i + 1];

        float m = fmaxf(l0, l1);
        float lse = m + logf(expf(l0 - m) + expf(l1 - m));
        float lp = (labels[i] ? l1 : l0) - lse;
        float ce = -lp;
        float pt = expf(lp);
        float om = 1.f - pt;
        float focal = om * om * ce;

        const float Tinv = 1.f / 3.f;
        float s0 = l0 * Tinv, s1 = l1 * Tinv;
        float ms = fmaxf(s0, s1);
        float lses = ms + logf(expf(s0 - ms) + expf(s1 - ms));
        float sl0 = s0 - lses, sl1 = s1 - lses;
        float t0 = logf(soft[2 * i] + 1e-8f) * Tinv;
        float t1 = logf(soft[2 * i + 1] + 1e-8f) * Tinv;
        float mt = fmaxf(t0, t1);
        float lset = mt + logf(expf(t0 - mt) + expf(t1 - mt));
        float tl0 = t0 - lset, tl1 = t1 - lset;
        float p0 = expf(tl0), p1 = expf(tl1);
        float kd = p0 * (tl0 - sl0) + p1 * (tl1 - sl1);

        float fs = waveReduceSum(focal);
        float ks = waveReduceSum(kd);
        __shared__ float sf[4], sk[4];
        if (lane == 0) { sf[wave] = fs; sk[wave] = ks; }
        __syncthreads();
        if (tid == 0) {
            fpart[bid] = sf[0] + sf[1] + sf[2] + sf[3];
            kpart[bid] = sk[0] + sk[1] + sk[2] + sk[3];
        }
    }
}

// ---- pairwise d^2: BARRIER-FREE K-loop ----
// Block = 128 rows x 512 cols, 8 waves. A-panel (128 rows x K=512 bf16 = 128 KB)
// staged into LDS ONCE (single vmcnt(0)+barrier), XOR-swizzled
// (LDS[row][pos] = src chunk pos^(row&7), 16B chunks). Each wave then runs its
// 128x64 col-strip independently: B frags straight from L2 (no LDS, no sync),
// A frags from LDS, 512 MFMA/wave. Waves slip freely -> latency self-hiding.
// XCD swizzle: jb = blk&7 (m09 round-robin) pins each 512KB B-strip in one L2.
__global__ __launch_bounds__(512, 2) void pairwise_free_kernel(const short* __restrict__ featbf,
                                                               const float* __restrict__ sqn,
                                                               const int* __restrict__ labels,
                                                               unsigned* __restrict__ posmax,
                                                               unsigned* __restrict__ negmin) {
    __shared__ short Alds[128 * 512];  // 128 KB
    const int tid = threadIdx.x;
    const int jb = blockIdx.x & 7, ib = blockIdx.x >> 3;
    const int wid = tid >> 6, lane = tid & 63;
    const int lo = lane & 15, hi = lane >> 4;

    // ---- stage A-panel: 16 issues; issue q = rows q*8..q*8+7, wave wid does row q*8+wid.
    // Wave-uniform LDS dest (row base); HW adds lane*16B -> position = lane;
    // source chunk = lane ^ (row&7)  (involution swizzle, rule #21).
    {
        const int row = wid;  // + q*8
        const short* gsrc = featbf + (size_t)(ib * 128 + row) * D_FEAT + ((lane ^ (row & 7)) * 8);
#pragma unroll
        for (int q = 0; q < 16; ++q) {
            // row_q = q*8 + wid; swizzle term depends on row_q&7 == wid&7 (q*8 keeps low 3 bits)
            GLOAD_LDS16(gsrc + (size_t)(q * 8) * D_FEAT, Alds + (q * 8 + row) * 512);
        }
    }

    // B fragment global pointers: wave strip cols = jb*512 + wid*64
    const short* gB[4];
#pragma unroll
    for (int n = 0; n < 4; ++n)
        gB[n] = featbf + (size_t)(jb * 512 + wid * 64 + n * 16 + lo) * D_FEAT + hi * 8;

    f32x4 acc[8][4];
#pragma unroll
    for (int m = 0; m < 8; ++m)
#pragma unroll
        for (int n = 0; n < 4; ++n)
            acc[m][n] = (f32x4){0.f, 0.f, 0.f, 0.f};

    // A-frag address components: row r = m*16 + lo; chunk(kk,hi) stored at
    // pos = (kk*4+hi) ^ (r&7); offset_shorts = r*512 + pos*8
    int r512[8], r7[8];
#pragma unroll
    for (int m = 0; m < 8; ++m) {
        int r = m * 16 + lo;
        r512[m] = r * 512;
        r7[m] = r & 7;
    }

    asm volatile("s_waitcnt vmcnt(0)" ::: "memory");
    __syncthreads();  // the ONLY K-loop barrier: A-panel resident

#pragma unroll 2
    for (int kk = 0; kk < D_FEAT / 32; ++kk) {
        s16x8 bfr[4], af[8];
#pragma unroll
        for (int n = 0; n < 4; ++n)
            bfr[n] = *(const s16x8*)(gB[n] + kk * 32);
#pragma unroll
        for (int m = 0; m < 8; ++m)
            af[m] = *(const s16x8*)(Alds + r512[m] + (((kk * 4 + hi) ^ r7[m]) * 8));
#pragma unroll
        for (int m = 0; m < 8; ++m)
#pragma unroll
            for (int n = 0; n < 4; ++n)
                acc[m][n] = __builtin_amdgcn_mfma_f32_16x16x32_bf16(af[m], bfr[n],
                                                                   acc[m][n], 0, 0, 0);
    }

    // ---- epilogue in d^2 domain (C/D layout m89: col = lo, row = hi*4 + reg) ----
    // All 8 waves cover the SAME 128 rows (different col strips): per-wave 16-lane
    // shfl reduce -> LDS cross-wave reduce (reuse Alds) -> 1 atomic pair/row/block.
    int coln[4], labc[4];
    float sqc[4];
#pragma unroll
    for (int n = 0; n < 4; ++n) {
        coln[n] = jb * 512 + wid * 64 + n * 16 + lo;
        labc[n] = labels[coln[n]];
        sqc[n] = sqn[coln[n]];
    }
    __syncthreads();  // all waves done reading A before LDS reuse
    float (*redp)[9] = (float(*)[9])Alds;          // [128][9]
    float (*redn)[9] = ((float(*)[9])Alds) + 128;  // [128][9]

#pragma unroll
    for (int m = 0; m < 8; ++m) {
#pragma unroll
        for (int r = 0; r < 4; ++r) {
            int row_loc = m * 16 + hi * 4 + r;
            int row_g = ib * 128 + row_loc;
            int labr = labels[row_g];
            float sqr = sqn[row_g];
            float pm = 0.f, nm = 1e12f;
#pragma unroll
            for (int n = 0; n < 4; ++n) {
                float d2 = fmaxf(sqr + fmaf(-2.f, acc[m][n][r], sqc[n]), 0.f);
                bool same = (labr == labc[n]);
                if (same) {
                    if (row_g != coln[n]) pm = fmaxf(pm, d2);
                } else {
                    nm = fminf(nm, d2);
                }
            }
#pragma unroll
            for (int off = 1; off < 16; off <<= 1) {
                pm = fmaxf(pm, __shfl_xor(pm, off));
                nm = fminf(nm, __shfl_xor(nm, off));
            }
            if (lo == 0) {
                redp[row_loc][wid] = pm;
                redn[row_loc][wid] = nm;
            }
        }
    }
    __syncthreads();
    if (tid < 128) {
        float p = redp[tid][0];
#pragma unroll
        for (int w = 1; w < 8; ++w) p = fmaxf(p, redp[tid][w]);
        atomicMax(&posmax[ib * 128 + tid], __float_as_uint(p));
    } else if (tid < 256) {
        int row = tid - 128;
        float nn = redn[row][0];
#pragma unroll
        for (int w = 1; w < 8; ++w) nn = fminf(nn, redn[row][w]);
        atomicMin(&negmin[ib * 128 + row], __float_as_uint(nn));
    }
}

// ---- final reduction + scalar combine (sqrt deferred to here; float32 outputs) ----
__global__ __launch_bounds__(256) void finalize_kernel(const unsigned* __restrict__ posmax,
                                                       const unsigned* __restrict__ negmin,
                                                       const float* __restrict__ fpart,
                                                       const float* __restrict__ kpart,
                                                       float* __restrict__ out) {
    int tid = threadIdx.x;
    float sum_pr = 0.f, sum_v = 0.f;
    for (int i = tid; i < B_ROWS; i += 256) {
        float p2 = __uint_as_float(posmax[i]);
        float n2 = __uint_as_float(negmin[i]);
        float v = (p2 > 0.f) ? 1.f : 0.f;
        sum_pr += fmaxf(sqrtf(p2) - sqrtf(n2) + 0.3f, 0.f) * v;
        sum_v += v;
    }
    sum_pr = waveReduceSum(sum_pr);
    sum_v = waveReduceSum(sum_v);
    __shared__ float sp[4], sv[4];
    int wave = tid >> 6, lane = tid & 63;
    if (lane == 0) { sp[wave] = sum_pr; sv[wave] = sum_v; }
    __syncthreads();
    if (tid == 0) {
        float spr = sp[0] + sp[1] + sp[2] + sp[3];
        float svv = sv[0] + sv[1] + sv[2] + sv[3];
        float fsum = 0.f, ksum = 0.f;
        for (int b = 0; b < 16; ++b) { fsum += fpart[b]; ksum += kpart[b]; }
        float focal = fsum / 4096.f;
        float kd = ksum / 4096.f * 9.f;  // * T^2
        float triplet = (svv > 0.f) ? spr / fmaxf(svv, 1.f) : 0.f;
        float total = focal + 0.5f * triplet + kd;
        out[0] = total;
        out[1] = focal;
        out[2] = triplet;
        out[3] = kd;
    }
}

extern "C" void kernel_launch(void* const* d_in, const int* in_sizes, int n_in,
                              void* d_out, int out_size, void* d_ws, size_t ws_size,
                              hipStream_t stream) {
    const float* logits = (const float*)d_in[0];
    const float* feat   = (const float*)d_in[1];
    const int*   labels = (const int*)d_in[2];
    const float* soft   = (const float*)d_in[3];

    char* ws = (char*)d_ws;
    unsigned* posmax = (unsigned*)ws;                    // 4096 u32 (d^2 bits)
    unsigned* negmin = (unsigned*)(ws + 16384);          // 4096 u32 (d^2 bits)
    float*    sqn    = (float*)(ws + 32768);             // 4096 f32
    float*    fpart  = (float*)(ws + 49152);             // 16 f32
    float*    kpart  = (float*)(ws + 49152 + 256);       // 16 f32
    short*    featbf = (short*)(ws + 65536);             // 4096*512 bf16 = 4 MB

    prep_kernel<<<1024, 256, 0, stream>>>(feat, logits, labels, soft, featbf, sqn,
                                          posmax, (float*)negmin, fpart, kpart);
    pairwise_free_kernel<<<256, 512, 0, stream>>>(featbf, sqn, labels, posmax, negmin);
    finalize_kernel<<<1, 256, 0, stream>>>(posmax, negmin, fpart, kpart,
                                           (float*)d_out);
}